// Round 2
// baseline (51563.837 us; speedup 1.0000x reference)
//
#include <hip/hip_runtime.h>

typedef unsigned short ushort_t;
typedef unsigned int uint32;
typedef __attribute__((ext_vector_type(8))) __bf16 bf16x8;
typedef __attribute__((ext_vector_type(4))) float f32x4;

#define BB 64
#define LL 1024
#define DD 64
#define HH 512
#define HSEQ_N (BB * LL * HH)           // 33554432
#define HN_OFF HSEQ_N
#define XH_OFF (HSEQ_N + BB * HH)       // 33587200

__device__ __forceinline__ float bf2f(ushort_t u) {
  union { uint32 i; float f; } v; v.i = ((uint32)u) << 16; return v.f;
}
__device__ __forceinline__ ushort_t f2bf(float f) {
  union { float f; uint32 i; } v; v.f = f;
  uint32 r = (v.i + 0x7fffu + ((v.i >> 16) & 1u)) >> 16;
  return (ushort_t)r;
}
__device__ __forceinline__ __bf16 u2b(ushort_t u) {
  union { ushort_t u; __bf16 b; } v; v.u = u; return v.b;
}
__device__ __forceinline__ float sigm(float x) { return 1.0f / (1.0f + __expf(-x)); }
__device__ __forceinline__ float tanh_f(float x) {
  x = fminf(20.f, fmaxf(-20.f, x));
  float e = __expf(2.0f * x);
  return (e - 1.0f) / (e + 1.0f);
}

// ---- dtype-agnostic loads/stores (BF = buffers are bf16, else fp32) ----
template<bool BF> __device__ __forceinline__ float ldf(const void* p, int i) {
  if constexpr (BF) return bf2f(((const ushort_t*)p)[i]);
  else return ((const float*)p)[i];
}
template<bool BF> __device__ __forceinline__ ushort_t ldb(const void* p, int i) {
  if constexpr (BF) return ((const ushort_t*)p)[i];
  else return f2bf(((const float*)p)[i]);
}
template<bool BF> __device__ __forceinline__ uint32 ld2(const void* p, int i) {
  if constexpr (BF) return *(const uint32*)((const ushort_t*)p + i);
  else {
    float2 v = *(const float2*)((const float*)p + i);
    return (uint32)f2bf(v.x) | ((uint32)f2bf(v.y) << 16);
  }
}
template<bool BF> __device__ __forceinline__ bf16x8 ld8(const void* p, int i) {
  if constexpr (BF) {
    return *(const bf16x8*)((const ushort_t*)p + i);
  } else {
    const float* f = (const float*)p + i;
    float4 a = *(const float4*)f;
    float4 b = *(const float4*)(f + 4);
    bf16x8 r;
    r[0] = u2b(f2bf(a.x)); r[1] = u2b(f2bf(a.y)); r[2] = u2b(f2bf(a.z)); r[3] = u2b(f2bf(a.w));
    r[4] = u2b(f2bf(b.x)); r[5] = u2b(f2bf(b.y)); r[6] = u2b(f2bf(b.z)); r[7] = u2b(f2bf(b.w));
    return r;
  }
}
template<bool BF> __device__ __forceinline__ void stf(void* p, int i, float v) {
  if constexpr (BF) ((ushort_t*)p)[i] = f2bf(v);
  else ((float*)p)[i] = v;
}

// Persistent GRU: 4 blocks (16 batch rows each, M=16 MFMA), no inter-block sync.
template<bool BF>
__device__ __forceinline__ void gru_body(
    const void* __restrict__ x, const void* __restrict__ h0,
    const void* __restrict__ Wih, const void* __restrict__ Whh,
    const void* __restrict__ bih, const void* __restrict__ bhh,
    const void* __restrict__ gamma, const void* __restrict__ beta,
    void* __restrict__ out,
    ushort_t* Abuf, ushort_t* xbuf, float* psum, float* psq)
{
  const int tid = threadIdx.x;
  const int w = tid >> 6;      // wave 0..15
  const int lane = tid & 63;
  const int lo = lane & 15;    // A-row / B-col / D-col
  const int hi = lane >> 4;    // quad
  const int b0 = blockIdx.x * 16;

  int cb[6];
  #pragma unroll
  for (int i = 0; i < 6; ++i) cb[i] = (i >> 1) * HH + w * 32 + (i & 1) * 16;
  const int j0 = w * 32 + lo;
  const int j1 = j0 + 16;

  float brz[4], bin[2], bhn[2];
  #pragma unroll
  for (int i = 0; i < 4; ++i) brz[i] = ldf<BF>(bih, cb[i] + lo) + ldf<BF>(bhh, cb[i] + lo);
  bin[0] = ldf<BF>(bih, cb[4] + lo); bin[1] = ldf<BF>(bih, cb[5] + lo);
  bhn[0] = ldf<BF>(bhh, cb[4] + lo); bhn[1] = ldf<BF>(bhh, cb[5] + lo);
  float gam[2] = { ldf<BF>(gamma, j0), ldf<BF>(gamma, j1) };
  float bet[2] = { ldf<BF>(beta, j0),  ldf<BF>(beta, j1) };

  float hprev[2][4];
  #pragma unroll
  for (int i = 0; i < 4; ++i) {
    int row = hi * 4 + i;
    ushort_t u0 = ldb<BF>(h0, (b0 + row) * HH + j0);
    ushort_t u1 = ldb<BF>(h0, (b0 + row) * HH + j1);
    hprev[0][i] = bf2f(u0); hprev[1][i] = bf2f(u1);
    Abuf[row * 520 + j0] = u0; Abuf[row * 520 + j1] = u1;
  }
  xbuf[w * 80 + lane] = ldb<BF>(x, ((b0 + w) * LL + 0) * DD + lane);

  const int wih_i = lo * DD + hi * 8;
  const int whh_i = lo * HH + hi * 8;

  __syncthreads();

  for (int t = 0; t < LL; ++t) {
    int t1 = (t + 1 < LL) ? (t + 1) : (LL - 1);
    ushort_t xr = ldb<BF>(x, ((b0 + w) * LL + t1) * DD + lane);

    f32x4 acc[6], ghn[2];
    #pragma unroll
    for (int i = 0; i < 6; ++i) acc[i] = {0.f, 0.f, 0.f, 0.f};
    ghn[0] = {0.f, 0.f, 0.f, 0.f}; ghn[1] = {0.f, 0.f, 0.f, 0.f};

    #pragma unroll
    for (int ks = 0; ks < 2; ++ks) {
      bf16x8 av = *(const bf16x8*)&xbuf[lo * 80 + ks * 32 + hi * 8];
      #pragma unroll
      for (int i = 0; i < 6; ++i) {
        bf16x8 bv = ld8<BF>(Wih, wih_i + cb[i] * DD + ks * 32);
        acc[i] = __builtin_amdgcn_mfma_f32_16x16x32_bf16(av, bv, acc[i], 0, 0, 0);
      }
    }
    #pragma unroll
    for (int ks = 0; ks < 16; ++ks) {
      bf16x8 av = *(const bf16x8*)&Abuf[lo * 520 + ks * 32 + hi * 8];
      #pragma unroll
      for (int i = 0; i < 4; ++i) {
        bf16x8 bv = ld8<BF>(Whh, whh_i + cb[i] * HH + ks * 32);
        acc[i] = __builtin_amdgcn_mfma_f32_16x16x32_bf16(av, bv, acc[i], 0, 0, 0);
      }
      #pragma unroll
      for (int T = 0; T < 2; ++T) {
        bf16x8 bv = ld8<BF>(Whh, whh_i + cb[4 + T] * HH + ks * 32);
        ghn[T] = __builtin_amdgcn_mfma_f32_16x16x32_bf16(av, bv, ghn[T], 0, 0, 0);
      }
    }

    #pragma unroll
    for (int T = 0; T < 2; ++T) {
      #pragma unroll
      for (int i = 0; i < 4; ++i) {
        float r = sigm(acc[T][i] + brz[T]);
        float z = sigm(acc[2 + T][i] + brz[2 + T]);
        float n = tanh_f(acc[4 + T][i] + bin[T] + r * (ghn[T][i] + bhn[T]));
        hprev[T][i] = z * (hprev[T][i] - n) + n;
      }
    }

    float sv[4], sq[4];
    #pragma unroll
    for (int i = 0; i < 4; ++i) {
      float v = hprev[0][i] + hprev[1][i];
      float q = hprev[0][i] * hprev[0][i] + hprev[1][i] * hprev[1][i];
      #pragma unroll
      for (int m = 1; m < 16; m <<= 1) {
        v += __shfl_xor(v, m, 64);
        q += __shfl_xor(q, m, 64);
      }
      sv[i] = v; sq[i] = q;
    }

    __syncthreads();  // A: all MFMA reads of Abuf/xbuf complete

    #pragma unroll
    for (int i = 0; i < 4; ++i) {
      int row = hi * 4 + i;
      Abuf[row * 520 + j0] = f2bf(hprev[0][i]);
      Abuf[row * 520 + j1] = f2bf(hprev[1][i]);
    }
    xbuf[w * 80 + lane] = xr;
    if (lo == 0) {
      #pragma unroll
      for (int i = 0; i < 4; ++i) {
        psum[w * 16 + hi * 4 + i] = sv[i];
        psq[w * 16 + hi * 4 + i] = sq[i];
      }
    }

    __syncthreads();  // B: h_t / x_{t+1} / partials visible

    float mu_l = 0.f, rs_l = 0.f;
    if (lane < 16) {
      float s = 0.f, ss = 0.f;
      #pragma unroll
      for (int ww = 0; ww < 16; ++ww) { s += psum[ww * 16 + lane]; ss += psq[ww * 16 + lane]; }
      mu_l = s * (1.0f / 512.0f);
      float var = ss * (1.0f / 512.0f) - mu_l * mu_l;
      rs_l = rsqrtf(var + 1e-5f);
    }
    float mu[4], rs[4];
    #pragma unroll
    for (int i = 0; i < 4; ++i) {
      mu[i] = __shfl(mu_l, hi * 4 + i, 64);
      rs[i] = __shfl(rs_l, hi * 4 + i, 64);
    }

    #pragma unroll
    for (int i = 0; i < 4; ++i) {
      int row = hi * 4 + i;
      float y0 = (hprev[0][i] - mu[i]) * rs[i] * gam[0] + bet[0];
      float y1 = (hprev[1][i] - mu[i]) * rs[i] * gam[1] + bet[1];
      int base = ((b0 + row) * LL + t) * HH;
      stf<BF>(out, base + j0, y0);
      stf<BF>(out, base + j1, y1);
    }
    if (t == LL - 1) {
      #pragma unroll
      for (int i = 0; i < 4; ++i) {
        int row = hi * 4 + i;
        stf<BF>(out, HN_OFF + (b0 + row) * HH + j0, hprev[0][i]);
        stf<BF>(out, HN_OFF + (b0 + row) * HH + j1, hprev[1][i]);
      }
    }
  }
}

__global__ __launch_bounds__(1024) void gru_kernel(
    const void* __restrict__ x, const void* __restrict__ h0,
    const void* __restrict__ Wih, const void* __restrict__ Whh,
    const void* __restrict__ bih, const void* __restrict__ bhh,
    const void* __restrict__ gamma, const void* __restrict__ beta,
    void* __restrict__ out)
{
  __shared__ __align__(16) ushort_t Abuf[16 * 520];
  __shared__ __align__(16) ushort_t xbuf[16 * 80];
  __shared__ float psum[256], psq[256];
  const bool bf = (((const ushort_t*)gamma)[0] == 0x3F80u);
  if (bf) gru_body<true>(x, h0, Wih, Whh, bih, bhh, gamma, beta, out, Abuf, xbuf, psum, psq);
  else    gru_body<false>(x, h0, Wih, Whh, bih, bhh, gamma, beta, out, Abuf, xbuf, psum, psq);
}

// x_hat = h_seq @ W_pred^T + b_pred (reads h_seq back from out region).
template<bool BF>
__device__ __forceinline__ void pred_body(
    void* __restrict__ out, const void* __restrict__ Wp, const void* __restrict__ bp,
    uint32* WL, uint32* hb)
{
  const int tid = threadIdx.x;
  const int d = tid & 63;
  const int rg = tid >> 6;

  for (int idx = tid; idx < 64 * 256; idx += 256) {
    int dd = idx >> 8, k2 = idx & 255;
    WL[k2 * 64 + ((dd + k2) & 63)] = ld2<BF>(Wp, dd * HH + k2 * 2);
  }
  float bpf = ldf<BF>(bp, d);
  __syncthreads();

  const int R0 = blockIdx.x * 64;
  for (int c = 0; c < 16; ++c) {
    #pragma unroll
    for (int ii = 0; ii < 4; ++ii) {
      int idx = ii * 256 + tid;
      int r = idx >> 8, k2 = idx & 255;
      hb[r * 256 + k2] = ld2<BF>(out, (R0 + c * 4 + r) * HH + k2 * 2);
    }
    __syncthreads();
    float acc = 0.f;
    #pragma unroll 8
    for (int k2 = 0; k2 < 256; ++k2) {
      uint32 wv = WL[k2 * 64 + ((d + k2) & 63)];
      uint32 hv = hb[rg * 256 + k2];
      union { uint32 i; float f; } a0, a1, c0, c1;
      a0.i = wv << 16; a1.i = wv & 0xffff0000u;
      c0.i = hv << 16; c1.i = hv & 0xffff0000u;
      acc += a0.f * c0.f + a1.f * c1.f;
    }
    stf<BF>(out, XH_OFF + (R0 + c * 4 + rg) * DD + d, acc + bpf);
    __syncthreads();
  }
}

__global__ __launch_bounds__(256) void pred_kernel(
    void* __restrict__ out, const void* __restrict__ Wp, const void* __restrict__ bp,
    const void* __restrict__ gamma)
{
  __shared__ uint32 WL[64 * 256];
  __shared__ uint32 hb[4 * 256];
  const bool bf = (((const ushort_t*)gamma)[0] == 0x3F80u);
  if (bf) pred_body<true>(out, Wp, bp, WL, hb);
  else    pred_body<false>(out, Wp, bp, WL, hb);
}

extern "C" void kernel_launch(void* const* d_in, const int* in_sizes, int n_in,
                              void* d_out, int out_size, void* d_ws, size_t ws_size,
                              hipStream_t stream) {
  const void* x   = d_in[0];
  const void* h0  = d_in[1];
  const void* Wih = d_in[2];
  const void* Whh = d_in[3];
  const void* bih = d_in[4];
  const void* bhh = d_in[5];
  const void* gam = d_in[6];
  const void* bet = d_in[7];
  const void* Wp  = d_in[8];
  const void* bp  = d_in[9];

  hipLaunchKernelGGL(gru_kernel, dim3(4), dim3(1024), 0, stream,
                     x, h0, Wih, Whh, bih, bhh, gam, bet, d_out);
  hipLaunchKernelGGL(pred_kernel, dim3(1024), dim3(256), 0, stream,
                     d_out, Wp, bp, gam);
}

// Round 3
// 11367.632 us; speedup vs baseline: 4.5360x; 4.5360x over previous
//
#include <hip/hip_runtime.h>

typedef unsigned short ushort_t;
typedef unsigned int uint32;
typedef __attribute__((ext_vector_type(8))) __bf16 bf16x8;
typedef __attribute__((ext_vector_type(4))) float f32x4;

#define BB 64
#define LL 1024
#define DD 64
#define HH 512
#define HSEQ_N (BB * LL * HH)
#define HN_OFF HSEQ_N
#define XH_OFF (HSEQ_N + BB * HH)

#define NGRP 4          // batch groups (16 rows each)
#define NCOL 16         // column groups (32 cols each)
// d_ws layout: [0,1024) counters (one uint32 per group, 256B apart)
//              [1024, 1024+131072) h exchange: [par][g][16 rows][512] bf16
//              [132096, +32768) LN partials: [par][g][c][T*16+row] float2
#define WS_CNT_STRIDE 64
#define WS_HEX_OFF 1024
#define WS_PS_OFF (1024 + 2 * NGRP * 16 * 512 * 2)

__device__ __forceinline__ ushort_t f2bf(float f) {
  union { float f; uint32 i; } v; v.f = f;
  uint32 r = (v.i + 0x7fffu + ((v.i >> 16) & 1u)) >> 16;
  return (ushort_t)r;
}
__device__ __forceinline__ __bf16 u2b(ushort_t u) {
  union { ushort_t u; __bf16 b; } v; v.u = u; return v.b;
}
__device__ __forceinline__ bf16x8 cvt8(const float* p) {
  float4 a = *(const float4*)p;
  float4 b = *(const float4*)(p + 4);
  bf16x8 r;
  r[0] = u2b(f2bf(a.x)); r[1] = u2b(f2bf(a.y)); r[2] = u2b(f2bf(a.z)); r[3] = u2b(f2bf(a.w));
  r[4] = u2b(f2bf(b.x)); r[5] = u2b(f2bf(b.y)); r[6] = u2b(f2bf(b.z)); r[7] = u2b(f2bf(b.w));
  return r;
}
__device__ __forceinline__ float sigm(float x) { return 1.0f / (1.0f + __expf(-x)); }
__device__ __forceinline__ float tanh_f(float x) {
  x = fminf(20.f, fmaxf(-20.f, x));
  float e = __expf(2.0f * x);
  return (e - 1.0f) / (e + 1.0f);
}

// 64 blocks = 4 batch-groups x 16 col-groups. 384 threads = 6 waves; wave v
// owns gate s=v>>1 (r,z,n), col-subtile T=v&1 (16 cols). W_hh/W_ih fragments
// for the wave's 16 output rows live in 72 VGPRs for the whole kernel.
// Per-step inter-block h exchange via d_ws + monotonic per-group counter.
__global__ __launch_bounds__(384) void gru_kernel(
    const float* __restrict__ x, const float* __restrict__ h0,
    const float* __restrict__ Wih, const float* __restrict__ Whh,
    const float* __restrict__ bih, const float* __restrict__ bhh,
    const float* __restrict__ gamma, const float* __restrict__ beta,
    float* __restrict__ out, uint32* __restrict__ cnt,
    ushort_t* __restrict__ h_ex, float2* __restrict__ ps_ex)
{
  __shared__ __align__(16) ushort_t Abuf[16 * 520];   // h_{t-1} bf16 (full 512 cols)
  __shared__ __align__(16) ushort_t xbuf[16 * 80];    // x_t bf16
  __shared__ float grz[4][16 * 17];                   // sigmoid(r/z) tiles [s*2+T]
  __shared__ float2 statb[16];                        // (mu, rstd) per batch row

  const int tid = threadIdx.x;
  const int v = tid >> 6, lane = tid & 63, lo = lane & 15, hi = lane >> 4;
  const int s = v >> 1, T = v & 1;
  const int g = blockIdx.x & 3, c = blockIdx.x >> 2;  // same-g blocks 2 XCDs apart
  const int b0 = g * 16;
  const int colj = c * 32 + T * 16 + lo;              // h-index this lane produces
  const int rowW = s * HH + colj;                      // W row (gate-major 3H layout)

  // ---- weights into registers (bf16 fragments) ----
  bf16x8 wB[16], wI[2];
  {
    const float* wr = Whh + (size_t)rowW * HH + hi * 8;
    #pragma unroll
    for (int ks = 0; ks < 16; ++ks) wB[ks] = cvt8(wr + ks * 32);
    const float* wir = Wih + (size_t)rowW * DD + hi * 8;
    #pragma unroll
    for (int ks = 0; ks < 2; ++ks) wI[ks] = cvt8(wir + ks * 32);
  }
  const float bsum = bih[rowW] + bhh[rowW];  // r/z combined bias
  const float bgh = bhh[rowW];               // n: hidden-side bias
  const float bgi = bih[rowW];               // n: input-side bias

  float hprev[4], gmv = 0.f, btv = 0.f;
  if (s == 2) {
    gmv = gamma[colj]; btv = beta[colj];
    #pragma unroll
    for (int i = 0; i < 4; ++i) hprev[i] = h0[(size_t)(b0 + hi * 4 + i) * HH + colj];
  }

  // ---- stage h0 -> Abuf, x(0) -> xbuf ----
  for (int i = tid; i < 16 * 512; i += 384) {
    int row = i >> 9, col = i & 511;
    Abuf[row * 520 + col] = f2bf(h0[(size_t)(b0 + row) * HH + col]);
  }
  for (int i = tid; i < 1024; i += 384) {
    int row = i >> 6, d = i & 63;
    xbuf[row * 80 + d] = f2bf(x[((size_t)(b0 + row) * LL + 0) * DD + d]);
  }
  __syncthreads();

  uint32* mycnt = cnt + g * WS_CNT_STRIDE;

  for (int t = 0; t < LL; ++t) {
    // prefetch x(t+1) into regs (overlaps MFMA phase)
    float xr[3];
    {
      int t1 = (t + 1 < LL) ? (t + 1) : (LL - 1);
      int n = 0;
      for (int i = tid; i < 1024; i += 384, ++n)
        xr[n] = x[((size_t)(b0 + (i >> 6)) * LL + t1) * DD + (i & 63)];
    }

    // ---- MFMA phase: A from LDS, B from registers ----
    f32x4 a0, a1, agi;
    #pragma unroll
    for (int i = 0; i < 4; ++i) {
      a0[i] = (s < 2) ? bsum : bgh;
      a1[i] = 0.f;
      agi[i] = bgi;
    }
    #pragma unroll
    for (int ks = 0; ks < 2; ++ks) {
      bf16x8 av = *(const bf16x8*)&xbuf[lo * 80 + ks * 32 + hi * 8];
      if (s < 2) a0 = __builtin_amdgcn_mfma_f32_16x16x32_bf16(av, wI[ks], a0, 0, 0, 0);
      else       agi = __builtin_amdgcn_mfma_f32_16x16x32_bf16(av, wI[ks], agi, 0, 0, 0);
    }
    #pragma unroll
    for (int ks = 0; ks < 16; ++ks) {
      bf16x8 av = *(const bf16x8*)&Abuf[lo * 520 + ks * 32 + hi * 8];
      if (ks & 1) a1 = __builtin_amdgcn_mfma_f32_16x16x32_bf16(av, wB[ks], a1, 0, 0, 0);
      else        a0 = __builtin_amdgcn_mfma_f32_16x16x32_bf16(av, wB[ks], a0, 0, 0, 0);
    }
    f32x4 gacc;
    #pragma unroll
    for (int i = 0; i < 4; ++i) gacc[i] = a0[i] + a1[i];

    if (s < 2) {
      #pragma unroll
      for (int i = 0; i < 4; ++i) grz[s * 2 + T][(hi * 4 + i) * 17 + lo] = sigm(gacc[i]);
    }
    __syncthreads();  // C: r,z tiles visible

    if (s == 2) {
      float hn[4];
      #pragma unroll
      for (int i = 0; i < 4; ++i) {
        float r = grz[T][(hi * 4 + i) * 17 + lo];
        float z = grz[2 + T][(hi * 4 + i) * 17 + lo];
        float n = tanh_f(agi[i] + r * gacc[i]);
        hn[i] = z * (hprev[i] - n) + n;
      }
      ushort_t* hx = h_ex + (size_t)(((t & 1) * NGRP + g) * 16) * 512;
      #pragma unroll
      for (int i = 0; i < 4; ++i) hx[(hi * 4 + i) * 512 + colj] = f2bf(hn[i]);
      // LN partials over this wave's 16 cols
      #pragma unroll
      for (int i = 0; i < 4; ++i) {
        float sv = hn[i], sq = hn[i] * hn[i];
        #pragma unroll
        for (int m = 1; m < 16; m <<= 1) {
          sv += __shfl_xor(sv, m, 64);
          sq += __shfl_xor(sq, m, 64);
        }
        if (lo == 0) {
          float2* pp = ps_ex + (size_t)(((t & 1) * NGRP + g) * NCOL + c) * 32 + T * 16;
          pp[hi * 4 + i] = make_float2(sv, sq);
        }
      }
      if (t == LL - 1) {
        #pragma unroll
        for (int i = 0; i < 4; ++i)
          out[(size_t)HN_OFF + (size_t)(b0 + hi * 4 + i) * HH + colj] = hn[i];
      }
      #pragma unroll
      for (int i = 0; i < 4; ++i) hprev[i] = hn[i];
    }
    __syncthreads();  // D: drains all waves' exchange stores (vmcnt at barrier)

    if (tid == 0) {
      __hip_atomic_fetch_add(mycnt, 1u, __ATOMIC_RELEASE, __HIP_MEMORY_SCOPE_AGENT);
      uint32 tgt = (uint32)NCOL * (uint32)(t + 1);
      while (__hip_atomic_load(mycnt, __ATOMIC_RELAXED, __HIP_MEMORY_SCOPE_AGENT) < tgt)
        __builtin_amdgcn_s_sleep(2);
    }
    __syncthreads();  // E: whole block past the sync point
    __threadfence();  // acquire: invalidate L1/L2-stale lines before readback

    // ---- stage full h_t -> Abuf (16 KB), x(t+1) -> xbuf ----
    {
      const uint4* hx4 = (const uint4*)(h_ex + (size_t)(((t & 1) * NGRP + g) * 16) * 512);
      for (int i = tid; i < 1024; i += 384) {
        uint4 vv = hx4[i];
        int row = i >> 6, c16 = i & 63;
        *(uint4*)&Abuf[row * 520 + c16 * 8] = vv;
      }
      int n = 0;
      for (int i = tid; i < 1024; i += 384, ++n)
        xbuf[(i >> 6) * 80 + (i & 63)] = f2bf(xr[n]);
    }
    // wave 3: fold the 32 per-block LN partials into (mu, rstd) per row
    if (v == 3) {
      int r = lane >> 2, q = lane & 3;
      const float2* pp = ps_ex + (size_t)(((t & 1) * NGRP + g) * NCOL) * 32;
      float sv = 0.f, sq = 0.f;
      #pragma unroll
      for (int j = 0; j < 8; ++j) {
        int u = q * 8 + j;                       // u = c*2+T combo
        float2 f2 = pp[(u >> 1) * 32 + (u & 1) * 16 + r];
        sv += f2.x; sq += f2.y;
      }
      sv += __shfl_xor(sv, 1, 64); sq += __shfl_xor(sq, 1, 64);
      sv += __shfl_xor(sv, 2, 64); sq += __shfl_xor(sq, 2, 64);
      if (q == 0) {
        float mu = sv * (1.0f / 512.0f);
        float var = sq * (1.0f / 512.0f) - mu * mu;
        statb[r] = make_float2(mu, rsqrtf(var + 1e-5f));
      }
    }
    __syncthreads();  // F: Abuf/xbuf/stats ready

    if (s == 2) {     // hseq(t) write overlaps next step's MFMA phase
      #pragma unroll
      for (int i = 0; i < 4; ++i) {
        float2 st = statb[hi * 4 + i];
        float y = (hprev[i] - st.x) * st.y * gmv + btv;
        out[((size_t)(b0 + hi * 4 + i) * LL + t) * HH + colj] = y;
      }
    }
  }
}

// x_hat = h_seq @ W_pred^T + b_pred (reads h_seq from out region, fp32).
__global__ __launch_bounds__(256) void pred_kernel(
    float* __restrict__ out, const float* __restrict__ Wp, const float* __restrict__ bp)
{
  __shared__ uint32 WL[64 * 256];  // [k2][(d+k2)&63] = bf16x2 of W[d][2k2..]
  __shared__ uint32 hb[4 * 256];
  const int tid = threadIdx.x;
  const int d = tid & 63;
  const int rg = tid >> 6;

  for (int idx = tid; idx < 64 * 256; idx += 256) {
    int dd = idx >> 8, k2 = idx & 255;
    float2 w2 = *(const float2*)&Wp[(size_t)dd * HH + k2 * 2];
    WL[k2 * 64 + ((dd + k2) & 63)] = (uint32)f2bf(w2.x) | ((uint32)f2bf(w2.y) << 16);
  }
  float bpf = bp[d];
  __syncthreads();

  const int R0 = blockIdx.x * 64;
  for (int c = 0; c < 16; ++c) {
    #pragma unroll
    for (int ii = 0; ii < 4; ++ii) {
      int idx = ii * 256 + tid;
      int r = idx >> 8, k2 = idx & 255;
      float2 h2 = *(const float2*)&out[(size_t)(R0 + c * 4 + r) * HH + k2 * 2];
      hb[r * 256 + k2] = (uint32)f2bf(h2.x) | ((uint32)f2bf(h2.y) << 16);
    }
    __syncthreads();
    float acc = 0.f;
    #pragma unroll 8
    for (int k2 = 0; k2 < 256; ++k2) {
      uint32 wv = WL[k2 * 64 + ((d + k2) & 63)];
      uint32 hv = hb[rg * 256 + k2];
      union { uint32 i; float f; } a0, a1, c0, c1;
      a0.i = wv << 16; a1.i = wv & 0xffff0000u;
      c0.i = hv << 16; c1.i = hv & 0xffff0000u;
      acc += a0.f * c0.f + a1.f * c1.f;
    }
    out[(size_t)XH_OFF + (size_t)(R0 + c * 4 + rg) * DD + d] = acc + bpf;
    __syncthreads();
  }
}

extern "C" void kernel_launch(void* const* d_in, const int* in_sizes, int n_in,
                              void* d_out, int out_size, void* d_ws, size_t ws_size,
                              hipStream_t stream) {
  const float* x   = (const float*)d_in[0];
  const float* h0  = (const float*)d_in[1];
  const float* Wih = (const float*)d_in[2];
  const float* Whh = (const float*)d_in[3];
  const float* bih = (const float*)d_in[4];
  const float* bhh = (const float*)d_in[5];
  const float* gam = (const float*)d_in[6];
  const float* bet = (const float*)d_in[7];
  const float* Wp  = (const float*)d_in[8];
  const float* bp  = (const float*)d_in[9];
  float* out = (float*)d_out;

  uint32* cnt    = (uint32*)d_ws;
  ushort_t* h_ex = (ushort_t*)((char*)d_ws + WS_HEX_OFF);
  float2* ps_ex  = (float2*)((char*)d_ws + WS_PS_OFF);

  // counters must start at 0 every launch (harness poisons d_ws with 0xAA)
  hipMemsetAsync(d_ws, 0, 1024, stream);

  hipLaunchKernelGGL(gru_kernel, dim3(NGRP * NCOL), dim3(384), 0, stream,
                     x, h0, Wih, Whh, bih, bhh, gam, bet, out, cnt, h_ex, ps_ex);
  hipLaunchKernelGGL(pred_kernel, dim3(1024), dim3(256), 0, stream,
                     out, Wp, bp);
}